// Round 8
// baseline (400.377 us; speedup 1.0000x reference)
//
#include <hip/hip_runtime.h>
#include <math.h>

typedef __attribute__((ext_vector_type(8))) short bf16x8;
typedef __attribute__((ext_vector_type(4))) short bf16x4;
typedef __attribute__((ext_vector_type(4))) float f32x4;
typedef __attribute__((ext_vector_type(16))) float f32x16;

#define MFMA16(a, b, c) __builtin_amdgcn_mfma_f32_16x16x32_bf16(a, b, c, 0, 0, 0)
#define MFMA32(a, b, c) __builtin_amdgcn_mfma_f32_32x32x16_bf16(a, b, c, 0, 0, 0)

#define GLOAD_LDS16(g, l)                                                        \
    __builtin_amdgcn_global_load_lds(                                            \
        (const __attribute__((address_space(1))) void*)(g),                      \
        (__attribute__((address_space(3))) void*)(l), 16, 0, 0)

__device__ __forceinline__ short f2bf(float f) {
    union { float f; unsigned u; } x; x.f = f;
    unsigned r = (x.u + 0x7fffu + ((x.u >> 16) & 1u)) >> 16;
    return (short)r;
}

__device__ __forceinline__ f32x16 zero16() {
    f32x16 z;
#pragma unroll
    for (int i = 0; i < 16; i++) z[i] = 0.f;
    return z;
}

// ---------------- elementwise fp32 -> bf16 ----------------
__global__ __launch_bounds__(256) void convert_bf16_kernel(
    const float* __restrict__ in, short* __restrict__ out, int n4) {
    int i = blockIdx.x * 256 + threadIdx.x;
    if (i >= n4) return;
    float4 v = ((const float4*)in)[i];
    bf16x4 o;
    o[0] = f2bf(v.x); o[1] = f2bf(v.y); o[2] = f2bf(v.z); o[3] = f2bf(v.w);
    ((bf16x4*)out)[i] = o;
}

// ------- fused transpose+convert for both weights: W[K][N] fp32 -> Wt[N][K] bf16 -----
__global__ __launch_bounds__(256) void transpose_w2_kernel(
    const float* __restrict__ Wa, const float* __restrict__ Wp,
    short* __restrict__ WaT, short* __restrict__ WpT) {
    __shared__ float tile[32][33];
    const float* W; short* Wt; int N, xb;
    if (blockIdx.x < 96) { W = Wa; Wt = WaT; N = 3072; xb = blockIdx.x; }
    else                 { W = Wp; Wt = WpT; N = 1024; xb = blockIdx.x - 96; }
    const int K = 1024;
    int c = threadIdx.x & 31, r0 = threadIdx.x >> 5;
    int n0 = xb << 5, k0 = blockIdx.y << 5;
#pragma unroll
    for (int i = 0; i < 4; i++) {
        int r = r0 + i * 8;
        tile[r][c] = W[(long)(k0 + r) * N + n0 + c];
    }
    __syncthreads();
#pragma unroll
    for (int i = 0; i < 4; i++) {
        int r = r0 + i * 8;
        Wt[(long)(n0 + r) * K + k0 + c] = f2bf(tile[c][r]);
    }
}

// ---------------- QKV GEMM (m97 pattern): 128x128 tile, K=1024 ----------------
// n-blocks 0-15 -> Q (scaled) / K rows into QK[4096][2048] bf16 (coalesced);
// n-blocks 16-23 -> V: LDS-transpose -> VT[B,H,64,2048] bf16.
__global__ __launch_bounds__(256) void gemm_qkv_kernel(
    const short* __restrict__ A, const short* __restrict__ Bt,
    const float* __restrict__ bias,
    short* __restrict__ QK, short* __restrict__ VTb, int Kdim) {
    __shared__ __align__(16) short lsAll[17408];  // lsA[8192] | lsB[8192]; V-epi: 4x64x68
    short* lsA = lsAll;
    short* lsB = lsAll + 8192;
    const int tid = threadIdx.x;
    const int lane = tid & 63, l15 = lane & 15, quad = lane >> 4;
    const int w = tid >> 6, wm = w >> 1, wn = w & 1;
    const int m0 = blockIdx.y * 128, n0 = blockIdx.x * 128;
    const int e = l15 & 7;
    const int lrow = lane >> 3;
    const int lgcol = ((lane & 7) ^ lrow) << 3;

    f32x4 acc[4][4];
#pragma unroll
    for (int i = 0; i < 4; i++)
#pragma unroll
        for (int j = 0; j < 4; j++) acc[i][j] = (f32x4){0.f, 0.f, 0.f, 0.f};

    for (int k0 = 0; k0 < Kdim; k0 += 64) {
#pragma unroll
        for (int ii = 0; ii < 4; ii++) {
            const int i = (w << 2) + ii;
            const int grow = (i << 3) + lrow;
            GLOAD_LDS16(&A[(size_t)(m0 + grow) * Kdim + k0 + lgcol], &lsA[i * 512]);
            GLOAD_LDS16(&Bt[(size_t)(n0 + grow) * Kdim + k0 + lgcol], &lsB[i * 512]);
        }
        __syncthreads();
#pragma unroll
        for (int kk = 0; kk < 64; kk += 32) {
            const int kb = kk >> 3;
            bf16x8 af[4], bfr[4];
#pragma unroll
            for (int t = 0; t < 4; t++) {
                const int sw = (((kb + quad) ^ e) << 3);
                af[t] = *(const bf16x8*)&lsA[(wm * 64 + t * 16 + l15) * 64 + sw];
                bfr[t] = *(const bf16x8*)&lsB[(wn * 64 + t * 16 + l15) * 64 + sw];
            }
#pragma unroll
            for (int mt = 0; mt < 4; mt++)
#pragma unroll
                for (int nt = 0; nt < 4; nt++)
                    acc[mt][nt] = MFMA16(af[mt], bfr[nt], acc[mt][nt]);
        }
        __syncthreads();  // final: also protects lsAll reuse in V-epilogue
    }

    if (n0 < 2048) {
        const float scale = (n0 < 1024) ? 0.18033688011112042f : 1.0f;  // 1/8 * log2(e)
#pragma unroll
        for (int nt = 0; nt < 4; nt++) {
            int nn = n0 + wn * 64 + nt * 16 + l15;
            float bv = bias[nn];
#pragma unroll
            for (int mt = 0; mt < 4; mt++)
#pragma unroll
                for (int r = 0; r < 4; r++) {
                    int mm = m0 + wm * 64 + mt * 16 + quad * 4 + r;
                    QK[(long)mm * 2048 + nn] = f2bf((acc[mt][nt][r] + bv) * scale);
                }
        }
    } else {
        short* vt = &lsAll[w * (64 * 68)];
#pragma unroll
        for (int nt = 0; nt < 4; nt++) {
            int nn = n0 + wn * 64 + nt * 16 + l15;
            float bv = bias[nn];
#pragma unroll
            for (int mt = 0; mt < 4; mt++) {
                bf16x4 pk;
#pragma unroll
                for (int r = 0; r < 4; r++) pk[r] = f2bf(acc[mt][nt][r] + bv);
                *(bf16x4*)&vt[(nt * 16 + l15) * 68 + mt * 16 + quad * 4] = pk;
            }
        }
        const int hh = ((n0 - 2048) >> 6) + wn;
        const int bb = m0 >> 11;
        const int srow = (m0 & 2047) + wm * 64;
        const int sloc = (lane & 7) << 3;
#pragma unroll
        for (int i = 0; i < 8; i++) {
            const int d = i * 8 + (lane >> 3);
            bf16x8 vv = *(const bf16x8*)&vt[d * 68 + sloc];
            *(bf16x8*)&VTb[((size_t)(bb * 16 + hh) * 64 + d) * 2048 + srow + sloc] = vv;
        }
    }
}

// ---------------- proj GEMM: 128x64 tile (512 blocks = 2/CU) ----------------
__global__ __launch_bounds__(256) void gemm_proj_kernel(
    const short* __restrict__ A, const short* __restrict__ Bt,
    const float* __restrict__ bias, float* __restrict__ outF) {
    __shared__ __align__(16) short lsA[128 * 64];
    __shared__ __align__(16) short lsB[64 * 64];
    const int tid = threadIdx.x;
    const int lane = tid & 63, l15 = lane & 15, quad = lane >> 4, w = tid >> 6;
    const int m0 = blockIdx.y * 128, n0 = blockIdx.x * 64;
    const int e = l15 & 7;
    const int lrow = lane >> 3;
    const int lgcol = ((lane & 7) ^ lrow) << 3;

    f32x4 acc[2][4];
#pragma unroll
    for (int i = 0; i < 2; i++)
#pragma unroll
        for (int j = 0; j < 4; j++) acc[i][j] = (f32x4){0.f, 0.f, 0.f, 0.f};

    for (int k0 = 0; k0 < 1024; k0 += 64) {
#pragma unroll
        for (int ii = 0; ii < 4; ii++) {
            const int i = (w << 2) + ii;
            const int grow = (i << 3) + lrow;
            GLOAD_LDS16(&A[(size_t)(m0 + grow) * 1024 + k0 + lgcol], &lsA[i * 512]);
        }
#pragma unroll
        for (int ii = 0; ii < 2; ii++) {
            const int i = (w << 1) + ii;
            const int grow = (i << 3) + lrow;
            GLOAD_LDS16(&Bt[(size_t)(n0 + grow) * 1024 + k0 + lgcol], &lsB[i * 512]);
        }
        __syncthreads();
#pragma unroll
        for (int kk = 0; kk < 64; kk += 32) {
            const int kb = kk >> 3;
            const int sw = (((kb + quad) ^ e) << 3);
            bf16x8 af[2], bfr[4];
#pragma unroll
            for (int mt = 0; mt < 2; mt++)
                af[mt] = *(const bf16x8*)&lsA[(w * 32 + mt * 16 + l15) * 64 + sw];
#pragma unroll
            for (int nt = 0; nt < 4; nt++)
                bfr[nt] = *(const bf16x8*)&lsB[(nt * 16 + l15) * 64 + sw];
#pragma unroll
            for (int mt = 0; mt < 2; mt++)
#pragma unroll
                for (int nt = 0; nt < 4; nt++)
                    acc[mt][nt] = MFMA16(af[mt], bfr[nt], acc[mt][nt]);
        }
        __syncthreads();
    }

#pragma unroll
    for (int nt = 0; nt < 4; nt++) {
        int nn = n0 + nt * 16 + l15;
        float bv = bias[nn];
#pragma unroll
        for (int mt = 0; mt < 2; mt++)
#pragma unroll
            for (int r = 0; r < 4; r++) {
                int mm = m0 + w * 32 + mt * 16 + quad * 4 + r;
                outF[(long)mm * 1024 + nn] = acc[mt][nt][r] + bv;
            }
    }
}

// ---------------- causal flash attention, key-split (flash-decoding) -----------------
// Block = 128 q rows x up to 8 key-chunks (64 keys each). No-max softmax => partials
// are additive: single-segment tiles (qt<4) normalize+write bf16 directly; split tiles
// atomically add fp32 (o, l) into O_acc/l_acc (combine kernel normalizes).
// Wave = 32 q (mfma_32x32x16). NOTE: per-lane l covers only half the key rows
// (row = ... + 4*hi) — must shfl_xor(32) before the gated atomic (R7 bug: missing
// shfl halved l for split tiles -> 2x output, absmax 8.3e-2).
__global__ __launch_bounds__(256, 3) void attn_kernel(
    const short* __restrict__ QK, const short* __restrict__ VT,
    short* __restrict__ Ao, float* __restrict__ O_acc, float* __restrict__ l_acc) {
    __shared__ __align__(16) short Kt[2][64 * 64];  // 16 KB
    __shared__ __align__(16) short Vt[2][64 * 64];  // 16 KB
    __shared__ __align__(16) short Pt[4][32 * 64];  // 16 KB (per-wave private)
    const int tid = threadIdx.x;
    const int lane = tid & 63, col = lane & 31, hi = lane >> 5, w = tid >> 6;
    const int bx = blockIdx.x;
    const int hb = bx & 31;          // b*16 + h
    const int sid = 39 - (bx >> 5);  // segment id within head; long segments first
    int qt, s;
    if (sid < 4)       { qt = sid;                 s = 0; }
    else if (sid < 12) { qt = 4 + ((sid - 4) >> 1);  s = (sid - 4) & 1; }
    else if (sid < 24) { qt = 8 + (sid - 12) / 3;    s = (sid - 12) % 3; }
    else               { qt = 12 + ((sid - 24) >> 2); s = (sid - 24) & 3; }
    const int nct = 2 * qt + 2;            // total 64-key chunks for this q-tile
    const int c0 = s * 8;
    const int c1 = (c0 + 8 < nct) ? c0 + 8 : nct;
    const bool single = (qt < 4);          // one segment covers everything

    const int b = hb >> 4, h = hb & 15;
    const size_t rowbase = (size_t)b * 2048 * 2048 + h * 64;
    const short* Qb = QK + rowbase;          // q row: + qs*2048 + d
    const short* Kb = QK + rowbase + 1024;   // k row: + ks*2048 + d
    const short* Vh = VT + (size_t)hb * 64 * 2048;  // [64][2048]
    short* Pw = &Pt[w][0];

    // staging geometry (rows 0..63 of a 64x64 tile, swizzled phys16Bcol = log ^ (row&7))
    const int srow0 = tid >> 3, sc40 = (tid & 7) ^ (srow0 & 7);
    const int srow1 = srow0 + 32, sc41 = (tid & 7) ^ (srow1 & 7);
    const int sdst0 = srow0 * 64 + ((tid & 7) << 3);
    const int sdst1 = srow1 * 64 + ((tid & 7) << 3);

    const int qloc = w * 32 + col;
    const int qglob = qt * 128 + qloc;

    // Q fragments (B-operand: n=col=q, k = kc*16 + hi*8 + j = d)
    bf16x8 qf[4];
#pragma unroll
    for (int kc = 0; kc < 4; kc++)
        qf[kc] = *(const bf16x8*)&Qb[(long)qglob * 2048 + kc * 16 + hi * 8];

    float l = 0.f;
    f32x16 o[2];
    o[0] = zero16(); o[1] = zero16();

    const int ca = 2 * qt + (w >> 1);  // this wave's diagonal chunk

    // stage chunk c0
    {
        const int kk0 = c0 * 64;
        *(bf16x8*)&Kt[0][sdst0] = *(const bf16x8*)&Kb[(size_t)(kk0 + srow0) * 2048 + sc40 * 8];
        *(bf16x8*)&Kt[0][sdst1] = *(const bf16x8*)&Kb[(size_t)(kk0 + srow1) * 2048 + sc41 * 8];
        *(bf16x8*)&Vt[0][sdst0] = *(const bf16x8*)&Vh[srow0 * 2048 + kk0 + sc40 * 8];
        *(bf16x8*)&Vt[0][sdst1] = *(const bf16x8*)&Vh[srow1 * 2048 + kk0 + sc41 * 8];
    }
    __syncthreads();

    for (int c = c0; c < c1; c++) {
        const short* Kc = &Kt[c & 1][0];
        const short* Vc = &Vt[c & 1][0];
        const bool more = (c + 1 < c1);
        bf16x8 kr0, kr1, vr0, vr1;
        if (more) {
            const int k2 = (c + 1) * 64;
            kr0 = *(const bf16x8*)&Kb[(size_t)(k2 + srow0) * 2048 + sc40 * 8];
            kr1 = *(const bf16x8*)&Kb[(size_t)(k2 + srow1) * 2048 + sc41 * 8];
            vr0 = *(const bf16x8*)&Vh[srow0 * 2048 + k2 + sc40 * 8];
            vr1 = *(const bf16x8*)&Vh[srow1 * 2048 + k2 + sc41 * 8];
        }

        if (c <= ca) {  // wave-uniform skip of fully-masked chunks
            f32x16 sx[2];
#pragma unroll
            for (int t = 0; t < 2; t++) {
                f32x16 z = zero16();
#pragma unroll
                for (int kc = 0; kc < 4; kc++) {
                    const int row = t * 32 + col;
                    bf16x8 kf = *(const bf16x8*)&Kc[row * 64 + (((kc * 2 + hi) ^ (row & 7)) << 3)];
                    z = MFMA32(kf, qf[kc], z);
                }
                sx[t] = z;
            }

            if (c == ca) {  // diagonal chunk
#pragma unroll
                for (int t = 0; t < 2; t++) {
                    const int thresh = qloc + qt * 128 - c * 64 - t * 32;
#pragma unroll
                    for (int g = 0; g < 4; g++)
#pragma unroll
                        for (int r2 = 0; r2 < 4; r2++) {
                            const int row = r2 + 8 * g + 4 * hi;
                            if (row > thresh) sx[t][g * 4 + r2] = -INFINITY;
                        }
                }
            }

#pragma unroll
            for (int t = 0; t < 2; t++) {
#pragma unroll
                for (int g = 0; g < 4; g++) {
                    bf16x4 pw;
#pragma unroll
                    for (int r2 = 0; r2 < 4; r2++) {
                        float pv = __builtin_amdgcn_exp2f(sx[t][g * 4 + r2]);
                        l += pv;
                        pw[r2] = f2bf(pv);
                    }
                    *(bf16x4*)&Pw[col * 64 + (((t * 4 + g) ^ (col & 7)) << 3) + hi * 4] = pw;
                }
            }

            bf16x8 pf[4];
#pragma unroll
            for (int kc2 = 0; kc2 < 4; kc2++)
                pf[kc2] = *(const bf16x8*)&Pw[col * 64 + (((kc2 * 2 + hi) ^ (col & 7)) << 3)];

#pragma unroll
            for (int dt = 0; dt < 2; dt++) {
                const int vrow = dt * 32 + col;
#pragma unroll
                for (int kc2 = 0; kc2 < 4; kc2++) {
                    bf16x8 vf = *(const bf16x8*)&Vc[vrow * 64 + (((kc2 * 2 + hi) ^ (vrow & 7)) << 3)];
                    o[dt] = MFMA32(vf, pf[kc2], o[dt]);
                }
            }
        }

        if (more) {
            short* Kn = &Kt[(c + 1) & 1][0];
            short* Vn = &Vt[(c + 1) & 1][0];
            *(bf16x8*)&Kn[sdst0] = kr0;
            *(bf16x8*)&Kn[sdst1] = kr1;
            *(bf16x8*)&Vn[sdst0] = vr0;
            *(bf16x8*)&Vn[sdst1] = vr1;
        }
        __syncthreads();
    }

    if (single) {
        // complete tile: normalize locally, write bf16
        l += __shfl_xor(l, 32);
        const float rl = 1.f / l;
        const long base = ((long)(b * 2048 + qglob)) * 1024 + h * 64;
#pragma unroll
        for (int dt = 0; dt < 2; dt++) {
#pragma unroll
            for (int g = 0; g < 4; g++) {
                bf16x4 wv;
#pragma unroll
                for (int r2 = 0; r2 < 4; r2++) wv[r2] = f2bf(o[dt][g * 4 + r2] * rl);
                *(bf16x4*)&Ao[base + dt * 32 + g * 8 + hi * 4] = wv;
            }
        }
    } else {
        // partial: accumulate fp32 o and l. l is split across the two lane-halves
        // (key rows ...+4*hi) — combine across hi BEFORE the gated atomic (R7 fix).
        l += __shfl_xor(l, 32);
        const size_t obase = ((size_t)hb * 1536 + (qglob - 512)) * 64;
#pragma unroll
        for (int dt = 0; dt < 2; dt++)
#pragma unroll
            for (int g = 0; g < 4; g++)
#pragma unroll
                for (int r2 = 0; r2 < 4; r2++) {
                    const int d = dt * 32 + g * 8 + hi * 4 + r2;
                    unsafeAtomicAdd(&O_acc[obase + d], o[dt][g * 4 + r2]);
                }
        if (hi == 0) unsafeAtomicAdd(&l_acc[hb * 1536 + (qglob - 512)], l);
    }
}

// ---------------- combine: normalize accumulated partials, cast to bf16 ----------------
__global__ __launch_bounds__(256) void attn_combine_kernel(
    const float* __restrict__ O_acc, const float* __restrict__ l_acc,
    short* __restrict__ Ao) {
    const int g = blockIdx.x * 256 + threadIdx.x;   // 196608 threads
    const int row = g >> 2;                          // hb*1536 + (q-512)
    const int ds = (g & 3) << 4;                     // 16 d per thread
    const int hb = row / 1536, qm = row - hb * 1536;
    const int b = hb >> 4, h = hb & 15;
    const float rl = 1.f / l_acc[row];
    const float* src = &O_acc[(size_t)row * 64 + ds];
    bf16x8 w0, w1;
#pragma unroll
    for (int i = 0; i < 8; i++) w0[i] = f2bf(src[i] * rl);
#pragma unroll
    for (int i = 0; i < 8; i++) w1[i] = f2bf(src[8 + i] * rl);
    const long dst = ((long)(b * 2048 + qm + 512)) * 1024 + h * 64 + ds;
    *(bf16x8*)&Ao[dst] = w0;
    *(bf16x8*)&Ao[dst + 8] = w1;
}

extern "C" void kernel_launch(void* const* d_in, const int* in_sizes, int n_in,
                              void* d_out, int out_size, void* d_ws, size_t ws_size,
                              hipStream_t stream) {
    const float* hs = (const float*)d_in[0];
    const float* W_attn = (const float*)d_in[1];
    const float* b_attn = (const float*)d_in[2];
    const float* W_proj = (const float*)d_in[3];
    const float* b_proj = (const float*)d_in[4];
    float* out = (float*)d_out;

    const size_t MB = 1024 * 1024;
    char* ws = (char*)d_ws;
    short* hs_bf = (short*)ws;                         // [0,8): hs bf16; later attn_o
    short* attn_o = hs_bf;
    float* O_acc = (float*)(ws + 8 * MB);              // [8,20): 32x1536x64 fp32 (12 MB)
    short* WaT = (short*)(ws + 8 * MB);                // [8,14): dead after QKV gemm
    float* l_acc = (float*)(ws + 20 * MB);             // [20,20.19): 32x1536 fp32
    short* WpT = (short*)(ws + 20 * MB + 256 * 1024);  // [20.25,22.25)
    short* QK = (short*)(ws + 22 * MB + 256 * 1024);   // [22.25,38.25): [4096][2048] bf16
    short* VTb = (short*)(ws + 38 * MB + 256 * 1024);  // [38.25,46.25): [32][64][2048] bf16

    convert_bf16_kernel<<<4096, 256, 0, stream>>>(hs, hs_bf, 1048576);
    transpose_w2_kernel<<<dim3(128, 32), 256, 0, stream>>>(W_attn, W_proj, WaT, WpT);
    gemm_qkv_kernel<<<dim3(24, 32), 256, 0, stream>>>(hs_bf, WaT, b_attn, QK, VTb, 1024);
    // zero O_acc + l_acc (WaT is dead now; region overlaps it)
    hipMemsetAsync(ws + 8 * MB, 0, 12 * MB + 192 * 1024, stream);
    attn_kernel<<<1280, 256, 0, stream>>>(QK, VTb, attn_o, O_acc, l_acc);
    attn_combine_kernel<<<768, 256, 0, stream>>>(O_acc, l_acc, attn_o);
    gemm_proj_kernel<<<dim3(16, 32), 256, 0, stream>>>(attn_o, WpT, b_proj, out);
}

// Round 9
// 183.638 us; speedup vs baseline: 2.1803x; 2.1803x over previous
//
#include <hip/hip_runtime.h>
#include <math.h>

typedef __attribute__((ext_vector_type(8))) short bf16x8;
typedef __attribute__((ext_vector_type(4))) short bf16x4;
typedef __attribute__((ext_vector_type(4))) float f32x4;

#define MFMA16(a, b, c) __builtin_amdgcn_mfma_f32_16x16x32_bf16(a, b, c, 0, 0, 0)

#define GLOAD_LDS16(g, l)                                                        \
    __builtin_amdgcn_global_load_lds(                                            \
        (const __attribute__((address_space(1))) void*)(g),                      \
        (__attribute__((address_space(3))) void*)(l), 16, 0, 0)

__device__ __forceinline__ short f2bf(float f) {
    union { float f; unsigned u; } x; x.f = f;
    unsigned r = (x.u + 0x7fffu + ((x.u >> 16) & 1u)) >> 16;
    return (short)r;
}

// ---------------- elementwise fp32 -> bf16 ----------------
__global__ __launch_bounds__(256) void convert_bf16_kernel(
    const float* __restrict__ in, short* __restrict__ out, int n4) {
    int i = blockIdx.x * 256 + threadIdx.x;
    if (i >= n4) return;
    float4 v = ((const float4*)in)[i];
    bf16x4 o;
    o[0] = f2bf(v.x); o[1] = f2bf(v.y); o[2] = f2bf(v.z); o[3] = f2bf(v.w);
    ((bf16x4*)out)[i] = o;
}

// ------- fused transpose+convert for both weights: W[K][N] fp32 -> Wt[N][K] bf16 -----
__global__ __launch_bounds__(256) void transpose_w2_kernel(
    const float* __restrict__ Wa, const float* __restrict__ Wp,
    short* __restrict__ WaT, short* __restrict__ WpT) {
    __shared__ float tile[32][33];
    const float* W; short* Wt; int N, xb;
    if (blockIdx.x < 96) { W = Wa; Wt = WaT; N = 3072; xb = blockIdx.x; }
    else                 { W = Wp; Wt = WpT; N = 1024; xb = blockIdx.x - 96; }
    const int K = 1024;
    int c = threadIdx.x & 31, r0 = threadIdx.x >> 5;
    int n0 = xb << 5, k0 = blockIdx.y << 5;
#pragma unroll
    for (int i = 0; i < 4; i++) {
        int r = r0 + i * 8;
        tile[r][c] = W[(long)(k0 + r) * N + n0 + c];
    }
    __syncthreads();
#pragma unroll
    for (int i = 0; i < 4; i++) {
        int r = r0 + i * 8;
        Wt[(long)(n0 + r) * K + k0 + c] = f2bf(tile[c][r]);
    }
}

// ---------------- QKV GEMM (m97 pattern): 128x128 tile, K=1024 ----------------
// n-blocks 0-15 -> Q (scaled) / K rows into QK[4096][2048] bf16 (coalesced);
// n-blocks 16-23 -> V: LDS-transpose -> VT[B,H,64,2048] bf16.
__global__ __launch_bounds__(256) void gemm_qkv_kernel(
    const short* __restrict__ A, const short* __restrict__ Bt,
    const float* __restrict__ bias,
    short* __restrict__ QK, short* __restrict__ VTb, int Kdim) {
    __shared__ __align__(16) short lsAll[17408];  // lsA[8192] | lsB[8192]; V-epi: 4x64x68
    short* lsA = lsAll;
    short* lsB = lsAll + 8192;
    const int tid = threadIdx.x;
    const int lane = tid & 63, l15 = lane & 15, quad = lane >> 4;
    const int w = tid >> 6, wm = w >> 1, wn = w & 1;
    const int m0 = blockIdx.y * 128, n0 = blockIdx.x * 128;
    const int e = l15 & 7;
    const int lrow = lane >> 3;
    const int lgcol = ((lane & 7) ^ lrow) << 3;

    f32x4 acc[4][4];
#pragma unroll
    for (int i = 0; i < 4; i++)
#pragma unroll
        for (int j = 0; j < 4; j++) acc[i][j] = (f32x4){0.f, 0.f, 0.f, 0.f};

    for (int k0 = 0; k0 < Kdim; k0 += 64) {
#pragma unroll
        for (int ii = 0; ii < 4; ii++) {
            const int i = (w << 2) + ii;
            const int grow = (i << 3) + lrow;
            GLOAD_LDS16(&A[(size_t)(m0 + grow) * Kdim + k0 + lgcol], &lsA[i * 512]);
            GLOAD_LDS16(&Bt[(size_t)(n0 + grow) * Kdim + k0 + lgcol], &lsB[i * 512]);
        }
        __syncthreads();
#pragma unroll
        for (int kk = 0; kk < 64; kk += 32) {
            const int kb = kk >> 3;
            bf16x8 af[4], bfr[4];
#pragma unroll
            for (int t = 0; t < 4; t++) {
                const int sw = (((kb + quad) ^ e) << 3);
                af[t] = *(const bf16x8*)&lsA[(wm * 64 + t * 16 + l15) * 64 + sw];
                bfr[t] = *(const bf16x8*)&lsB[(wn * 64 + t * 16 + l15) * 64 + sw];
            }
#pragma unroll
            for (int mt = 0; mt < 4; mt++)
#pragma unroll
                for (int nt = 0; nt < 4; nt++)
                    acc[mt][nt] = MFMA16(af[mt], bfr[nt], acc[mt][nt]);
        }
        __syncthreads();  // final: also protects lsAll reuse in V-epilogue
    }

    if (n0 < 2048) {
        const float scale = (n0 < 1024) ? 0.18033688011112042f : 1.0f;  // 1/8 * log2(e)
#pragma unroll
        for (int nt = 0; nt < 4; nt++) {
            int nn = n0 + wn * 64 + nt * 16 + l15;
            float bv = bias[nn];
#pragma unroll
            for (int mt = 0; mt < 4; mt++)
#pragma unroll
                for (int r = 0; r < 4; r++) {
                    int mm = m0 + wm * 64 + mt * 16 + quad * 4 + r;
                    QK[(long)mm * 2048 + nn] = f2bf((acc[mt][nt][r] + bv) * scale);
                }
        }
    } else {
        short* vt = &lsAll[w * (64 * 68)];
#pragma unroll
        for (int nt = 0; nt < 4; nt++) {
            int nn = n0 + wn * 64 + nt * 16 + l15;
            float bv = bias[nn];
#pragma unroll
            for (int mt = 0; mt < 4; mt++) {
                bf16x4 pk;
#pragma unroll
                for (int r = 0; r < 4; r++) pk[r] = f2bf(acc[mt][nt][r] + bv);
                *(bf16x4*)&vt[(nt * 16 + l15) * 68 + mt * 16 + quad * 4] = pk;
            }
        }
        const int hh = ((n0 - 2048) >> 6) + wn;
        const int bb = m0 >> 11;
        const int srow = (m0 & 2047) + wm * 64;
        const int sloc = (lane & 7) << 3;
#pragma unroll
        for (int i = 0; i < 8; i++) {
            const int d = i * 8 + (lane >> 3);
            bf16x8 vv = *(const bf16x8*)&vt[d * 68 + sloc];
            *(bf16x8*)&VTb[((size_t)(bb * 16 + hh) * 64 + d) * 2048 + srow + sloc] = vv;
        }
    }
}

// ---------------- proj GEMM: 128x64 tile (512 blocks = 2/CU) ----------------
__global__ __launch_bounds__(256) void gemm_proj_kernel(
    const short* __restrict__ A, const short* __restrict__ Bt,
    const float* __restrict__ bias, float* __restrict__ outF) {
    __shared__ __align__(16) short lsA[128 * 64];
    __shared__ __align__(16) short lsB[64 * 64];
    const int tid = threadIdx.x;
    const int lane = tid & 63, l15 = lane & 15, quad = lane >> 4, w = tid >> 6;
    const int m0 = blockIdx.y * 128, n0 = blockIdx.x * 64;
    const int e = l15 & 7;
    const int lrow = lane >> 3;
    const int lgcol = ((lane & 7) ^ lrow) << 3;

    f32x4 acc[2][4];
#pragma unroll
    for (int i = 0; i < 2; i++)
#pragma unroll
        for (int j = 0; j < 4; j++) acc[i][j] = (f32x4){0.f, 0.f, 0.f, 0.f};

    for (int k0 = 0; k0 < 1024; k0 += 64) {
#pragma unroll
        for (int ii = 0; ii < 4; ii++) {
            const int i = (w << 2) + ii;
            const int grow = (i << 3) + lrow;
            GLOAD_LDS16(&A[(size_t)(m0 + grow) * 1024 + k0 + lgcol], &lsA[i * 512]);
        }
#pragma unroll
        for (int ii = 0; ii < 2; ii++) {
            const int i = (w << 1) + ii;
            const int grow = (i << 3) + lrow;
            GLOAD_LDS16(&Bt[(size_t)(n0 + grow) * 1024 + k0 + lgcol], &lsB[i * 512]);
        }
        __syncthreads();
#pragma unroll
        for (int kk = 0; kk < 64; kk += 32) {
            const int kb = kk >> 3;
            const int sw = (((kb + quad) ^ e) << 3);
            bf16x8 af[2], bfr[4];
#pragma unroll
            for (int mt = 0; mt < 2; mt++)
                af[mt] = *(const bf16x8*)&lsA[(w * 32 + mt * 16 + l15) * 64 + sw];
#pragma unroll
            for (int nt = 0; nt < 4; nt++)
                bfr[nt] = *(const bf16x8*)&lsB[(nt * 16 + l15) * 64 + sw];
#pragma unroll
            for (int mt = 0; mt < 2; mt++)
#pragma unroll
                for (int nt = 0; nt < 4; nt++)
                    acc[mt][nt] = MFMA16(af[mt], bfr[nt], acc[mt][nt]);
        }
        __syncthreads();
    }

#pragma unroll
    for (int nt = 0; nt < 4; nt++) {
        int nn = n0 + nt * 16 + l15;
        float bv = bias[nn];
#pragma unroll
        for (int mt = 0; mt < 2; mt++)
#pragma unroll
            for (int r = 0; r < 4; r++) {
                int mm = m0 + w * 32 + mt * 16 + quad * 4 + r;
                outF[(long)mm * 1024 + nn] = acc[mt][nt][r] + bv;
            }
    }
}

// ---------------- causal flash attention (R5 structure, best measured) ----------------
// Block = 64 q rows (4 waves x 16 q), 1024 blocks heavy-first. 64-key chunks
// double-buffered in LDS (XOR-swizzled). S^T = K*Q^T, O^T = V^T*P^T. No max-tracking
// (scores bounded after folded 1/8*log2e scale); per-lane partial l, 2 shuffles at end.
__global__ __launch_bounds__(256, 4) void attn_kernel(
    const short* __restrict__ QK, const short* __restrict__ VT,
    short* __restrict__ Ao) {
    __shared__ __align__(16) short Kt[2][64 * 64];  // 16 KB
    __shared__ __align__(16) short Vt[2][64 * 64];  // 16 KB
    __shared__ __align__(16) short Pt[4][1024];     // 8 KB (per-wave private)
    const int tid = threadIdx.x;
    const int lane = tid & 63, l15 = lane & 15, quad = lane >> 4, w = tid >> 6;
    const int bx = blockIdx.x;
    const int qt = 31 - (bx >> 5);  // heavy q-tiles first
    const int hb = bx & 31;         // b*16 + h
    const int b = hb >> 4, h = hb & 15;
    const size_t rowbase = (size_t)b * 2048 * 2048 + h * 64;
    const short* Qb = QK + rowbase;          // q row: + qs*2048 + d
    const short* Kb = QK + rowbase + 1024;   // k row: + ks*2048 + d
    const short* Vh = VT + (size_t)hb * 64 * 2048;  // [64][2048]
    short* Pw = &Pt[w][0];
    const int e = l15 & 7;

    // staging geometry (rows 0..63 of a 64x64 tile, swizzled c4 ^= row&7)
    const int srow0 = tid >> 3, sc40 = (tid & 7) ^ (srow0 & 7);
    const int srow1 = srow0 + 32, sc41 = (tid & 7) ^ (srow1 & 7);
    const int sdst0 = srow0 * 64 + ((tid & 7) << 3);
    const int sdst1 = srow1 * 64 + ((tid & 7) << 3);

    // Q fragments (B-operand: n=l15=q, k=quad*8+j=d)
    const long qr = (long)(qt * 64 + w * 16 + l15) * 2048;
    bf16x8 qf0 = *(const bf16x8*)&Qb[qr + quad * 8];
    bf16x8 qf1 = *(const bf16x8*)&Qb[qr + 32 + quad * 8];

    float l = 0.f;  // per-lane partial denominator
    f32x4 o[4];
#pragma unroll
    for (int dt = 0; dt < 4; dt++) o[dt] = (f32x4){0.f, 0.f, 0.f, 0.f};

    const int nc = qt + 1;  // 64-key chunks

    // stage chunk 0
    *(bf16x8*)&Kt[0][sdst0] = *(const bf16x8*)&Kb[(size_t)srow0 * 2048 + sc40 * 8];
    *(bf16x8*)&Kt[0][sdst1] = *(const bf16x8*)&Kb[(size_t)srow1 * 2048 + sc41 * 8];
    *(bf16x8*)&Vt[0][sdst0] = *(const bf16x8*)&Vh[srow0 * 2048 + sc40 * 8];
    *(bf16x8*)&Vt[0][sdst1] = *(const bf16x8*)&Vh[srow1 * 2048 + sc41 * 8];
    __syncthreads();

    for (int c = 0; c < nc; c++) {
        const short* Kc = &Kt[c & 1][0];
        const short* Vc = &Vt[c & 1][0];
        const bool more = (c + 1 < nc);
        bf16x8 kr0, kr1, vr0, vr1;
        if (more) {
            const int k2 = (c + 1) * 64;
            kr0 = *(const bf16x8*)&Kb[(size_t)(k2 + srow0) * 2048 + sc40 * 8];
            kr1 = *(const bf16x8*)&Kb[(size_t)(k2 + srow1) * 2048 + sc41 * 8];
            vr0 = *(const bf16x8*)&Vh[srow0 * 2048 + k2 + sc40 * 8];
            vr1 = *(const bf16x8*)&Vh[srow1 * 2048 + k2 + sc41 * 8];
        }

        // S^T: A = K tile rows (key), B = Q^T. C/D: col=l15=q, row=quad*4+r=key.
        f32x4 s[4];
#pragma unroll
        for (int t = 0; t < 4; t++) {
            bf16x8 k0f = *(const bf16x8*)&Kc[(t * 16 + l15) * 64 + ((quad ^ e) << 3)];
            bf16x8 k1f = *(const bf16x8*)&Kc[(t * 16 + l15) * 64 + (((4 + quad) ^ e) << 3)];
            f32x4 z = (f32x4){0.f, 0.f, 0.f, 0.f};
            z = MFMA16(k0f, qf0, z);
            z = MFMA16(k1f, qf1, z);
            s[t] = z;
        }

        if (c == nc - 1) {  // diagonal chunk: local key t*16+quad*4+r vs local q w*16+l15
#pragma unroll
            for (int t = 0; t < 4; t++)
#pragma unroll
                for (int r = 0; r < 4; r++)
                    if (t * 16 + quad * 4 + r > w * 16 + l15) s[t][r] = -INFINITY;
        }

        // P = exp2(s) straight: no max, no rescale. Accumulate l per-lane.
#pragma unroll
        for (int t = 0; t < 4; t++) {
            bf16x4 pw;
#pragma unroll
            for (int r = 0; r < 4; r++) {
                float pv = __builtin_amdgcn_exp2f(s[t][r]);
                l += pv;
                pw[r] = f2bf(pv);
            }
            *(bf16x4*)&Pw[l15 * 64 + (((2 * t + (quad >> 1)) ^ e) << 3) + ((quad & 1) << 2)] = pw;
        }

        // P^T as B-operand (same-wave ds_write->ds_read; compiler orders via lgkmcnt)
        bf16x8 pf0 = *(const bf16x8*)&Pw[l15 * 64 + ((quad ^ e) << 3)];
        bf16x8 pf1 = *(const bf16x8*)&Pw[l15 * 64 + (((4 + quad) ^ e) << 3)];
#pragma unroll
        for (int dt = 0; dt < 4; dt++) {
            bf16x8 v0f = *(const bf16x8*)&Vc[(dt * 16 + l15) * 64 + ((quad ^ e) << 3)];
            bf16x8 v1f = *(const bf16x8*)&Vc[(dt * 16 + l15) * 64 + (((4 + quad) ^ e) << 3)];
            o[dt] = MFMA16(v0f, pf0, o[dt]);
            o[dt] = MFMA16(v1f, pf1, o[dt]);
        }

        if (more) {
            short* Kn = &Kt[(c + 1) & 1][0];
            short* Vn = &Vt[(c + 1) & 1][0];
            *(bf16x8*)&Kn[sdst0] = kr0;
            *(bf16x8*)&Kn[sdst1] = kr1;
            *(bf16x8*)&Vn[sdst0] = vr0;
            *(bf16x8*)&Vn[sdst1] = vr1;
        }
        __syncthreads();
    }

    // denominator: combine the 4 key-quads once
    l += __shfl_xor(l, 16);
    l += __shfl_xor(l, 32);
    const float rl = 1.f / l;

    // O^T: row=quad*4+r = d within dt tile, col=l15 = q; 4 r-values contiguous in d
    const int qs = qt * 64 + w * 16 + l15;
    const long base = ((long)(b * 2048 + qs)) * 1024 + h * 64;
#pragma unroll
    for (int dt = 0; dt < 4; dt++) {
        bf16x4 wv;
#pragma unroll
        for (int r = 0; r < 4; r++) wv[r] = f2bf(o[dt][r] * rl);
        *(bf16x4*)&Ao[base + dt * 16 + quad * 4] = wv;
    }
}

extern "C" void kernel_launch(void* const* d_in, const int* in_sizes, int n_in,
                              void* d_out, int out_size, void* d_ws, size_t ws_size,
                              hipStream_t stream) {
    const float* hs = (const float*)d_in[0];
    const float* W_attn = (const float*)d_in[1];
    const float* b_attn = (const float*)d_in[2];
    const float* W_proj = (const float*)d_in[3];
    const float* b_proj = (const float*)d_in[4];
    float* out = (float*)d_out;

    const size_t MB = 1024 * 1024;
    char* ws = (char*)d_ws;
    short* hs_bf = (short*)ws;                   // [0,8): hs bf16; later attn_o (alias)
    short* attn_o = hs_bf;
    short* WaT = (short*)(ws + 8 * MB);          // [8,14): W_attn^T bf16
    short* WpT = (short*)(ws + 14 * MB);         // [14,16): W_proj^T bf16
    short* QK = (short*)(ws + 16 * MB);          // [16,32): [4096][2048] bf16
    short* VTb = (short*)(ws + 32 * MB);         // [32,40): [32][64][2048] bf16

    convert_bf16_kernel<<<4096, 256, 0, stream>>>(hs, hs_bf, 1048576);
    transpose_w2_kernel<<<dim3(128, 32), 256, 0, stream>>>(W_attn, W_proj, WaT, WpT);
    gemm_qkv_kernel<<<dim3(24, 32), 256, 0, stream>>>(hs_bf, WaT, b_attn, QK, VTb, 1024);
    attn_kernel<<<1024, 256, 0, stream>>>(QK, VTb, attn_o);
    gemm_proj_kernel<<<dim3(16, 32), 256, 0, stream>>>(attn_o, WpT, b_proj, out);
}